// Round 7
// baseline (146.122 us; speedup 1.0000x reference)
//
#include <hip/hip_runtime.h>

// Problem constants (from reference setup_inputs) — all tensors are fp32.
#define BATCH 16
#define NVEC 1024
#define NDIM 64
#define NHID 32
#define NW   10
#define NCLS 10
#define NOFF 11      // diag + 10 power-of-2 offsets (chord mask: 11 nnz/row)
#define WPAD 12      // padded weights-per-row so k_chain reads 3x float4

// ---------------------------------------------------------------------------
// Kernel 0: transpose fW2 [i][j][m] -> W2T [i][m][j] so the k_weights gather
// reads a row of consecutive j's as float4s. LDS-tiled, 1.3 MB total.
// ---------------------------------------------------------------------------
__global__ __launch_bounds__(256) void k_transpose(
    const float* __restrict__ fW2, float* __restrict__ W2T)
{
    __shared__ float tile[NHID][65];   // +1 pad: conflict-free transposed reads
    const int i = blockIdx.y;
    const int m0 = blockIdx.x * 64;
    const int t = threadIdx.x;
    const int tL = t & 63, wv = t >> 6;

    const float* src = fW2 + (size_t)i * NHID * NVEC;
    #pragma unroll
    for (int jj = 0; jj < 8; ++jj) {
        int j = wv * 8 + jj;
        tile[j][tL] = src[(size_t)j * NVEC + m0 + tL];   // 256B coalesced
    }
    __syncthreads();

    float* dst = W2T + (size_t)i * NVEC * NHID;
    const int j = t & 31, mrow = t >> 5;
    #pragma unroll
    for (int g = 0; g < 8; ++g) {
        int m = g * 8 + mrow;
        dst[(size_t)(m0 + m) * NHID + j] = tile[j][m];   // coalesced
    }
}

// ---------------------------------------------------------------------------
// Kernel 1: all sparse chord weights, all 10 layers (h depends only on data).
// Round-6 failure: 640 blocks = 2.5 waves/SIMD + serial 700-cyc L3 loads ->
// 20% VALUBusy, 53us. Fix: 4x waves by j-quartering. Thread = one (b,n) row
// x 8 hidden units; jq = WAVE index (readfirstlane) so the W1 slice stays
// wave-uniform -> s_load + SGPR-operand FMAs (no LDS in the hot loop, no
// spill at ~50 VGPR). The 4 jq partial dots per (row,offset) combine through
// an 11KB LDS buffer with one barrier. Bias b2[m] added by the single jq
// with (o&3)==jq, batched with the gather loads.
// grid (256 = 64 n-groups x 4 b-groups, NW), block 256 (4 waves).
// ---------------------------------------------------------------------------
__global__ __launch_bounds__(256, 4) void k_weights(
    const float* __restrict__ data,   // [B][NVEC][NDIM]
    const float* __restrict__ fW1,    // [NW][NDIM][NHID]
    const float* __restrict__ fb1,    // [NW][NHID]
    const float* __restrict__ W2T,    // [NW][NVEC][NHID]  (transposed fW2)
    const float* __restrict__ fb2,    // [NW][NVEC]
    float* __restrict__ Wsp)          // [NW][B][NVEC][WPAD]
{
    const int i    = blockIdx.y;
    const int t    = threadIdx.x;
    const int lane = t & 63;
    const int jq   = __builtin_amdgcn_readfirstlane(t >> 6);  // wave id 0..3
    const int j0   = jq * 8;
    const int nb   = blockIdx.x & 63;     // 64 n-groups of 16
    const int bb   = blockIdx.x >> 6;     // 4 b-groups of 4
    const int nl   = lane & 15;
    const int bq   = lane >> 4;
    const int n    = nb * 16 + nl;
    const int b    = bb * 4 + bq;

    __shared__ float comb[NOFF * 4][64];  // [o*4+jq][row] = 11 KB

    // h = b1 slice (wave-uniform scalar loads)
    const float* w1 = fW1 + (size_t)i * NDIM * NHID + j0;
    const float* b1 = fb1 + (size_t)i * NHID + j0;
    float h[8];
    #pragma unroll
    for (int jj = 0; jj < 8; ++jj) h[jj] = b1[jj];

    // h += data[b,n,:] @ W1[i][:, j0:j0+8]  (A streamed float4; W1 via SGPR)
    const float4* arow = (const float4*)(data + ((size_t)(b * NVEC) + n) * NDIM);
    #pragma unroll 4
    for (int g = 0; g < 16; ++g) {
        float4 a = arow[g];
        float xs[4] = {a.x, a.y, a.z, a.w};
        #pragma unroll
        for (int dk = 0; dk < 4; ++dk) {
            const float* wr = w1 + (g * 4 + dk) * NHID;   // wave-uniform
            float x = xs[dk];
            #pragma unroll
            for (int jj = 0; jj < 8; ++jj) h[jj] += x * wr[jj];
        }
    }

    // exact gelu on the 8 owned hidden units
    #pragma unroll
    for (int jj = 0; jj < 8; ++jj) {
        float x = h[jj];
        h[jj] = 0.5f * x * (1.0f + erff(x * 0.70710678118654752f));
    }

    // 11 sparse columns: partial dot over this thread's 8 j's
    const float* w2t = W2T + (size_t)i * NVEC * NHID + j0;
    const float* b2  = fb2 + (size_t)i * NVEC;
    #pragma unroll
    for (int o = 0; o < NOFF; ++o) {
        int off = (1 << o) >> 1;          // 0,1,2,4,...,512
        int m = (n + off) & (NVEC - 1);
        const float4* gp = (const float4*)(w2t + (size_t)m * NHID);
        float4 g0 = gp[0], g1 = gp[1];
        float p = h[0] * g0.x + h[1] * g0.y + h[2] * g0.z + h[3] * g0.w
                + h[4] * g1.x + h[5] * g1.y + h[6] * g1.z + h[7] * g1.w;
        if ((o & 3) == jq) p += b2[m];    // bias from exactly one jq
        comb[o * 4 + jq][lane] = p;       // consecutive lanes -> consecutive banks
    }
    __syncthreads();

    // combine 4 jq partials and store: 11 offsets x 64 rows = 704 items
    for (int idx = t; idx < NOFF * 64; idx += 256) {
        int o = idx >> 6, row = idx & 63;
        float s = comb[o * 4 + 0][row] + comb[o * 4 + 1][row]
                + comb[o * 4 + 2][row] + comb[o * 4 + 3][row];
        int rn = nb * 16 + (row & 15);
        int rb = bb * 4 + (row >> 4);
        Wsp[((size_t)(i * BATCH + rb) * NVEC + rn) * WPAD + o] = s;
    }
}

// ---------------------------------------------------------------------------
// Kernel 2: FUSED 10-layer chain + final-projection partials.
// Block = (b, 4-dim chunk): V[1024][4] slice closed under the chord gather,
// kept in LDS float4 (all gathers aligned ds_read_b128). 1024 threads =
// 16 waves. Next layer's 11 weights (3 float4, row-padded) prefetched into
// registers so the loads are in flight across the barrier. 1 barrier/layer.
// grid (16 chunks, BATCH), block 1024.
// ---------------------------------------------------------------------------
__global__ __launch_bounds__(1024) void k_chain(
    const float* __restrict__ data,   // [B][NVEC][NDIM]
    const float* __restrict__ Wsp,    // [NW][B][NVEC][WPAD]
    const float* __restrict__ Wf,     // [NVEC*NDIM][NCLS]
    float* __restrict__ part)         // [B][16][NCLS]
{
    const int chunk = blockIdx.x;
    const int b     = blockIdx.y;
    const int d0    = chunk * 4;
    const int n     = threadIdx.x;

    __shared__ float4 bufA[NVEC];
    __shared__ float4 bufB[NVEC];

    bufA[n] = *(const float4*)(data + ((size_t)(b * NVEC) + n) * NDIM + d0);

    // prefetch layer NW-1 weights
    const float4* wp = (const float4*)(Wsp + ((size_t)((NW - 1) * BATCH + b) * NVEC + n) * WPAD);
    float4 wa = wp[0], wb4 = wp[1], wc = wp[2];
    __syncthreads();

    float4* cur = bufA;
    float4* nxt = bufB;

    for (int l = 0; l < NW; ++l) {
        float4 na, nb, nc;
        if (l < NW - 1) {   // prefetch next layer (in flight across barrier)
            const float4* wpn = (const float4*)(
                Wsp + ((size_t)((NW - 2 - l) * BATCH + b) * NVEC + n) * WPAD);
            na = wpn[0]; nb = wpn[1]; nc = wpn[2];
        }
        const float wgt[12] = {wa.x, wa.y, wa.z, wa.w,
                               wb4.x, wb4.y, wb4.z, wb4.w,
                               wc.x, wc.y, wc.z, wc.w};
        float4 v0 = cur[n];
        float4 acc;
        acc.x = v0.x + wgt[0] * v0.x;
        acc.y = v0.y + wgt[0] * v0.y;
        acc.z = v0.z + wgt[0] * v0.z;
        acc.w = v0.w + wgt[0] * v0.w;
        #pragma unroll
        for (int o = 1; o < NOFF; ++o) {
            int off = 1 << (o - 1);
            float4 vv = cur[(n + off) & (NVEC - 1)];
            acc.x += wgt[o] * vv.x; acc.y += wgt[o] * vv.y;
            acc.z += wgt[o] * vv.z; acc.w += wgt[o] * vv.w;
        }
        nxt[n] = acc;
        __syncthreads();
        float4* tmp = cur; cur = nxt; nxt = tmp;
        if (l < NW - 1) { wa = na; wb4 = nb; wc = nc; }
    }

    // fused final projection partial over this (b, d-chunk)
    float p[NCLS];
    #pragma unroll
    for (int c = 0; c < NCLS; ++c) p[c] = 0.0f;
    {
        float4 vv = cur[n];
        float vs[4] = {vv.x, vv.y, vv.z, vv.w};
        const float4* wfv = (const float4*)(Wf + ((size_t)(n * NDIM + d0)) * NCLS);
        float wf[40];
        #pragma unroll
        for (int k = 0; k < 10; ++k) {
            float4 u = wfv[k];
            wf[k * 4 + 0] = u.x; wf[k * 4 + 1] = u.y;
            wf[k * 4 + 2] = u.z; wf[k * 4 + 3] = u.w;
        }
        #pragma unroll
        for (int d = 0; d < 4; ++d)
            #pragma unroll
            for (int cls = 0; cls < NCLS; ++cls)
                p[cls] += vs[d] * wf[d * NCLS + cls];
    }

    // reduce 1024 threads -> 10 values: wave shfl then cross-wave via LDS
    const int lane = n & 63, wv = n >> 6;   // 16 waves
    float* sred = (float*)nxt;              // dead buffer
    #pragma unroll
    for (int cls = 0; cls < NCLS; ++cls) {
        float v = p[cls];
        #pragma unroll
        for (int s = 32; s > 0; s >>= 1) v += __shfl_down(v, s, 64);
        if (lane == 0) sred[wv * NCLS + cls] = v;
    }
    __syncthreads();
    if (n < NCLS) {
        float s = 0.0f;
        #pragma unroll
        for (int w = 0; w < 16; ++w) s += sred[w * NCLS + n];
        part[(size_t)(b * 16 + chunk) * NCLS + n] = s;
    }
}

// ---------------------------------------------------------------------------
__global__ __launch_bounds__(256) void k_finish(
    const float* __restrict__ part, const float* __restrict__ bias,
    float* __restrict__ out)
{
    int t = threadIdx.x;
    if (t < BATCH * NCLS) {
        int b = t / NCLS, cls = t % NCLS;
        float s = bias[cls];
        #pragma unroll
        for (int ch = 0; ch < 16; ++ch) s += part[(size_t)(b * 16 + ch) * NCLS + cls];
        out[t] = s;
    }
}

// ---------------------------------------------------------------------------
extern "C" void kernel_launch(void* const* d_in, const int* in_sizes, int n_in,
                              void* d_out, int out_size, void* d_ws, size_t ws_size,
                              hipStream_t stream) {
    const float* data = (const float*)d_in[0];
    const float* fW1  = (const float*)d_in[1];
    const float* fb1  = (const float*)d_in[2];
    const float* fW2  = (const float*)d_in[3];
    const float* fb2  = (const float*)d_in[4];
    const float* fWf  = (const float*)d_in[5];
    const float* fbf  = (const float*)d_in[6];
    float* out = (float*)d_out;

    float* ws   = (float*)d_ws;
    float* Wsp  = ws;                                         // NW*B*NVEC*WPAD = 1,966,080 f
    float* W2T  = Wsp + (size_t)NW * BATCH * NVEC * WPAD;     // NW*NVEC*NHID  =   327,680 f
    float* part = W2T + (size_t)NW * NVEC * NHID;             // 2,560 f

    k_transpose<<<dim3(NVEC / 64, NW), 256, 0, stream>>>(fW2, W2T);
    k_weights<<<dim3(256, NW), 256, 0, stream>>>(
        data, fW1, fb1, W2T, fb2, Wsp);
    k_chain<<<dim3(NDIM / 4, BATCH), 1024, 0, stream>>>(data, Wsp, fWf, part);
    k_finish<<<dim3(1), 256, 0, stream>>>(part, fbf, out);
}